// Round 8
// baseline (491.380 us; speedup 1.0000x reference)
//
#include <hip/hip_runtime.h>
#include <hip/hip_fp16.h>

constexpr int NN = 100000;   // nodes
constexpr int NE = 1600000;  // edges
constexpr int NG = 256;      // graphs
constexpr int NBUCK = 391;   // node buckets of 256 (391*256 = 100096 >= NN)
constexpr int NBLK = 128;    // blocks for bucket hist/scatter
constexpr int EPB = NE / NBLK;  // 12500 edges per block
constexpr int GGRID = 2048;  // gather grid (8 blocks/CU = 32 waves/CU)
constexpr int NSLOT = 32;    // BN-stat accumulator slots (line-disjoint)

typedef _Float16 f16x8 __attribute__((ext_vector_type(8)));
typedef float f32x4 __attribute__((ext_vector_type(4)));

// ================= CSR build: two-level bucket counting sort =================
__global__ __launch_bounds__(256) void k_bhist(const int* __restrict__ ei,
                                               int* __restrict__ bcnt) {
  __shared__ int hc[NBUCK];
  int tid = threadIdx.x;
  for (int i = tid; i < NBUCK; i += 256) hc[i] = 0;
  __syncthreads();
  int e0 = blockIdx.x * EPB;
  for (int e = e0 + tid; e < e0 + EPB; e += 256) atomicAdd(&hc[ei[NE + e] >> 8], 1);
  __syncthreads();
  for (int i = tid; i < NBUCK; i += 256) bcnt[i * NBLK + blockIdx.x] = hc[i];
}

// ---- hierarchical scan of bcnt[NBUCK][NBLK] -> boff (exclusive, LOCAL) ----
__global__ __launch_bounds__(128) void k_scan1(const int* __restrict__ bcnt,
                                               int* __restrict__ boff,
                                               int* __restrict__ btot) {
  __shared__ int s[128];
  int t = threadIdx.x, b = blockIdx.x;
  int v = bcnt[b * NBLK + t];
  s[t] = v;
  __syncthreads();
  for (int off = 1; off < 128; off <<= 1) {
    int x = (t >= off) ? s[t - off] : 0;
    __syncthreads();
    s[t] += x;
    __syncthreads();
  }
  boff[b * NBLK + t] = s[t] - v;  // local exclusive (bbase added at use site)
  if (t == 127) btot[b] = s[127];
}

__global__ __launch_bounds__(512) void k_scan2(const int* __restrict__ btot,
                                               int* __restrict__ bbase) {
  __shared__ int s[512];
  int t = threadIdx.x;
  int v = (t < NBUCK) ? btot[t] : 0;
  s[t] = v;
  __syncthreads();
  for (int off = 1; off < 512; off <<= 1) {
    int x = (t >= off) ? s[t - off] : 0;
    __syncthreads();
    s[t] += x;
    __syncthreads();
  }
  if (t < NBUCK) bbase[t] = s[t] - v;  // exclusive
}

// bbase[] folded in at read time (k_scan3 eliminated from the dispatch chain)
__global__ __launch_bounds__(256) void k_bscatter(const int* __restrict__ ei,
                                                  const int* __restrict__ boff,
                                                  const int* __restrict__ bbase,
                                                  int* __restrict__ bpacked) {
  __shared__ int cur[NBUCK];
  int tid = threadIdx.x;
  for (int i = tid; i < NBUCK; i += 256)
    cur[i] = boff[i * NBLK + blockIdx.x] + bbase[i];
  __syncthreads();
  int e0 = blockIdx.x * EPB;
  for (int e = e0 + tid; e < e0 + EPB; e += 256) {
    int s = ei[e], d = ei[NE + e];
    int pos = atomicAdd(&cur[d >> 8], 1);
    bpacked[pos] = s | ((d & 255) << 17);  // src fits 17 bits (NN < 131072)
  }
}

// Per bucket: hist -> deg/dinv, local scan -> rs, cursor fill -> edata (src).
__global__ __launch_bounds__(256) void k_sortfill(const int* __restrict__ bpacked,
                                                  const int* __restrict__ boff,
                                                  const int* __restrict__ bbase,
                                                  float* __restrict__ dinv,
                                                  int* __restrict__ rs,
                                                  int* __restrict__ edata) {
  __shared__ int hist[256], scn[256], cur[256];
  int tid = threadIdx.x, b = blockIdx.x;
  int bs = boff[b * NBLK] + bbase[b];
  int be = (b + 1 < NBUCK) ? boff[(b + 1) * NBLK] + bbase[b + 1] : NE;
  hist[tid] = 0;
  __syncthreads();
  for (int i = bs + tid; i < be; i += 256) atomicAdd(&hist[bpacked[i] >> 17], 1);
  __syncthreads();
  int n = (b << 8) + tid;
  int hv = hist[tid];
  if (n < NN) dinv[n] = rsqrtf((float)(hv + 1));  // +1 self-loop
  scn[tid] = hv;
  __syncthreads();
  for (int off = 1; off < 256; off <<= 1) {
    int v = (tid >= off) ? scn[tid - off] : 0;
    __syncthreads();
    scn[tid] += v;
    __syncthreads();
  }
  int excl = scn[tid] - hv;
  if (n < NN) rs[n] = bs + excl;
  if (b == NBUCK - 1 && tid == 0) rs[NN] = NE;
  cur[tid] = bs + excl;
  __syncthreads();
  for (int i = bs + tid; i < be; i += 256) {
    int p = bpacked[i];
    int pos = atomicAdd(&cur[p >> 17], 1);
    edata[pos] = p & 131071;  // writes confined to [bs,be) ~17KB window
  }
}

// ------ W prep (fp16 transpose) + zero-init of pool/cnt/statsP (per iter) ----
// hWt layout: W1t[64][128] | W2t[64][64] | W3t[64][64]
__global__ __launch_bounds__(256) void k_wprep(const float* __restrict__ W1,
                                               const float* __restrict__ W2,
                                               const float* __restrict__ W3,
                                               __half* __restrict__ hWt,
                                               float* __restrict__ pool,
                                               float* __restrict__ cnt,
                                               float* __restrict__ statsP) {
  int t = blockIdx.x * 256 + threadIdx.x;
  int stride = gridDim.x * 256;
  for (int i = t; i < 128 * 64; i += stride) {
    int k = i >> 6, f = i & 63;
    hWt[f * 128 + k] = __float2half(W1[i]);
  }
  for (int i = t; i < 64 * 64; i += stride) {
    int k = i >> 6, f = i & 63;
    hWt[64 * 128 + f * 64 + k] = __float2half(W2[i]);
    hWt[64 * 128 + 64 * 64 + f * 64 + k] = __float2half(W3[i]);
  }
  for (int i = t; i < NG * 64; i += stride) pool[i] = 0.f;
  for (int i = t; i < NG; i += stride) cnt[i] = 0.f;
  for (int i = t; i < 3 * NSLOT * 128; i += stride) statsP[i] = 0.f;
}

// ====== GEMM (MFMA fp16): hq[n][64] = fp16( (f(in)[N][K] @ W[K][64]) * dinv[n] )
// LDS-FREE: each lane's B-fragment is 8 CONSECUTIVE fp32 of its row — load them
// directly (2x float4 per K-chunk), BN+ReLU+cvt in registers, MFMA. No staging
// chain (global->vmcnt->ds_write->lgkmcnt->ds_read) per tile. BN sc/sh built
// once per block in LDS from the 32 stat slots.
// Swapped-operand MFMA: A = W^T, B = X. Lane mapping for BOTH operands:
// matrix index = lane&15, k = (lane>>4)*8 + j. D: col=lane&15 -> node,
// row -> feature 16t+4q+reg. NN/16 = 6250 exactly -> no row guards.
template <int K, bool BN>
__global__ __launch_bounds__(256) void k_gemm(const float* __restrict__ in,
                                              const float* __restrict__ stats,
                                              const float* __restrict__ gam,
                                              const float* __restrict__ bet,
                                              const __half* __restrict__ Wt,
                                              const float* __restrict__ dinv,
                                              __half* __restrict__ hq) {
  constexpr int KC = K / 32;       // K-chunks of 32
  const int tid = threadIdx.x;
  const int lane = tid & 63;
  const int wv = tid >> 6;
  const int q = lane >> 4;         // 0..3
  const int r15 = lane & 15;

  __shared__ float scs[64], shs[64];
  if (BN) {
    if (tid < 64) {
      const float inv_n = 1.0f / NN;
      float ssum = 0.f, ssq = 0.f;
      for (int sl = 0; sl < NSLOT; sl++) {
        ssum += stats[sl * 128 + tid];
        ssq += stats[sl * 128 + 64 + tid];
      }
      float mean = ssum * inv_n;
      float var = ssq * inv_n - mean * mean;
      float s = gam[tid] * rsqrtf(var + 1e-5f);
      scs[tid] = s;
      shs[tid] = bet[tid] - mean * s;
    }
    __syncthreads();
  }

  // ---- W fragments in registers: one 16B load each (fp16 pre-transposed) ----
  f16x8 wf[KC][4];
#pragma unroll
  for (int t = 0; t < 4; t++)
#pragma unroll
    for (int kc = 0; kc < KC; kc++)
      wf[kc][t] = *reinterpret_cast<const f16x8*>(Wt + (16 * t + r15) * K + kc * 32 + q * 8);

  // per-lane BN params for this lane's input columns (kc*32 + q*8 + j)
  float scr[KC][8], shr[KC][8];
  if (BN) {
#pragma unroll
    for (int kc = 0; kc < KC; kc++)
#pragma unroll
      for (int j = 0; j < 8; j++) {
        int col = kc * 32 + q * 8 + j;
        scr[kc][j] = scs[col];
        shr[kc][j] = shs[col];
      }
  }

  constexpr int tiles = NN / 16;   // 6250 exact
  const int gwave = blockIdx.x * 4 + wv;
  const int nw = gridDim.x * 4;
  for (int tile = gwave; tile < tiles; tile += nw) {
    const int node = tile * 16 + r15;
    const float* rowp = in + (size_t)node * K;
    f16x8 xf[KC];
#pragma unroll
    for (int kc = 0; kc < KC; kc++) {
      float4 a = *reinterpret_cast<const float4*>(rowp + kc * 32 + q * 8);
      float4 b = *reinterpret_cast<const float4*>(rowp + kc * 32 + q * 8 + 4);
      if (BN) {
        a.x = fmaxf(a.x * scr[kc][0] + shr[kc][0], 0.f);
        a.y = fmaxf(a.y * scr[kc][1] + shr[kc][1], 0.f);
        a.z = fmaxf(a.z * scr[kc][2] + shr[kc][2], 0.f);
        a.w = fmaxf(a.w * scr[kc][3] + shr[kc][3], 0.f);
        b.x = fmaxf(b.x * scr[kc][4] + shr[kc][4], 0.f);
        b.y = fmaxf(b.y * scr[kc][5] + shr[kc][5], 0.f);
        b.z = fmaxf(b.z * scr[kc][6] + shr[kc][6], 0.f);
        b.w = fmaxf(b.w * scr[kc][7] + shr[kc][7], 0.f);
      }
      f16x8 x;
      x[0] = (_Float16)a.x; x[1] = (_Float16)a.y;
      x[2] = (_Float16)a.z; x[3] = (_Float16)a.w;
      x[4] = (_Float16)b.x; x[5] = (_Float16)b.y;
      x[6] = (_Float16)b.z; x[7] = (_Float16)b.w;
      xf[kc] = x;
    }

    f32x4 acc[4] = {f32x4{0.f, 0.f, 0.f, 0.f}, f32x4{0.f, 0.f, 0.f, 0.f},
                    f32x4{0.f, 0.f, 0.f, 0.f}, f32x4{0.f, 0.f, 0.f, 0.f}};
#pragma unroll
    for (int kc = 0; kc < KC; kc++)
#pragma unroll
      for (int t = 0; t < 4; t++)
        acc[t] = __builtin_amdgcn_mfma_f32_16x16x32_f16(wf[kc][t], xf[kc], acc[t], 0, 0, 0);

    const float dv = dinv[node];
#pragma unroll
    for (int t = 0; t < 4; t++) {
      union {
        __half2 h2[2];
        float2 f2;
      } u;
      u.h2[0] = __floats2half2_rn(acc[t][0] * dv, acc[t][1] * dv);
      u.h2[1] = __floats2half2_rn(acc[t][2] * dv, acc[t][3] * dv);
      *reinterpret_cast<float2*>(hq + (size_t)node * 64 + 16 * t + 4 * q) = u.f2;
    }
  }
}

// ====== Gather: agg[d] = dinv[d] * (sum_src h'[src] + h'[d]) ================
// h' = h*dinv (fp16, 128 B row). Wave = 2 nodes (lane<32: even, >=32: odd);
// per half: 4 streams of 8 lanes, lane owns 8 cols (16 B float4 = full row per
// 8-lane group). 2-deep unroll (r2-proven core). Streaming data (edata, agg)
// uses nontemporal hints so the randomly-reused hq stays L2/L3 resident.
// BN stats: block-reduced in LDS, one atomic/col into slot blockIdx&31.
__global__ __launch_bounds__(256) void k_gather(const __half* __restrict__ hq,
                                                const int* __restrict__ edata,
                                                const int* __restrict__ rs,
                                                const float* __restrict__ dinv,
                                                float* __restrict__ agg,
                                                float* __restrict__ statsP) {
  const int tid = threadIdx.x;
  const int lane = tid & 63;
  const int half = lane >> 5;      // 0: even node, 1: odd node
  const int hs = (lane >> 3) & 3;  // stream within half (0..3)
  const int cl = lane & 7;         // col group: cols 8*cl..8*cl+7 (16 B)
  const int wave = blockIdx.x * 4 + (tid >> 6);
  const int nwaves = GGRID * 4;
  float ss[8] = {0.f, 0.f, 0.f, 0.f, 0.f, 0.f, 0.f, 0.f};
  float sq[8] = {0.f, 0.f, 0.f, 0.f, 0.f, 0.f, 0.f, 0.f};
  constexpr int NPAIR = NN / 2;
#pragma unroll 1
  for (int pr = wave; pr < NPAIR; pr += nwaves) {
    const int node = 2 * pr + half;
    int e0 = rs[node], e1 = rs[node + 1];
    float a[8] = {0.f, 0.f, 0.f, 0.f, 0.f, 0.f, 0.f, 0.f};
    int e = e0 + hs;
#pragma unroll 1
    for (; e + 4 < e1; e += 8) {  // 2 edges per stream in flight
      int s0 = __builtin_nontemporal_load(edata + e);
      int s1 = __builtin_nontemporal_load(edata + e + 4);
      float4 r0 = ((const float4*)(hq + (size_t)s0 * 64))[cl];
      float4 r1 = ((const float4*)(hq + (size_t)s1 * 64))[cl];
      const __half2* h0 = (const __half2*)&r0;
      const __half2* h1 = (const __half2*)&r1;
#pragma unroll
      for (int i = 0; i < 4; i++) {
        float2 f = __half22float2(h0[i]);
        float2 g = __half22float2(h1[i]);
        a[2 * i] += f.x + g.x;
        a[2 * i + 1] += f.y + g.y;
      }
    }
    if (e < e1) {
      int s0 = __builtin_nontemporal_load(edata + e);
      float4 r0 = ((const float4*)(hq + (size_t)s0 * 64))[cl];
      const __half2* h0 = (const __half2*)&r0;
#pragma unroll
      for (int i = 0; i < 4; i++) {
        float2 f = __half22float2(h0[i]);
        a[2 * i] += f.x;
        a[2 * i + 1] += f.y;
      }
    }
    // combine the 4 streams of each half (2 levels; halves stay independent)
#pragma unroll
    for (int i = 0; i < 8; i++) {
      a[i] += __shfl_xor(a[i], 8);
      a[i] += __shfl_xor(a[i], 16);
    }
    if (hs == 0) {
      // self term + final scale by dinv[node]
      float4 rsv = ((const float4*)(hq + (size_t)node * 64))[cl];
      const __half2* hsv = (const __half2*)&rsv;
      float dv = dinv[node];
      float o[8];
#pragma unroll
      for (int i = 0; i < 4; i++) {
        float2 f = __half22float2(hsv[i]);
        o[2 * i] = (a[2 * i] + f.x) * dv;
        o[2 * i + 1] = (a[2 * i + 1] + f.y) * dv;
      }
      f32x4 o0 = {o[0], o[1], o[2], o[3]};
      f32x4 o1 = {o[4], o[5], o[6], o[7]};
      __builtin_nontemporal_store(o0, (f32x4*)(agg + (size_t)node * 64) + 2 * cl);
      __builtin_nontemporal_store(o1, (f32x4*)(agg + (size_t)node * 64) + 2 * cl + 1);
#pragma unroll
      for (int i = 0; i < 8; i++) {
        ss[i] += o[i];
        sq[i] += o[i] * o[i];
      }
    }
  }
  // fold odd-node-half stats into lanes 0-7, LDS-reduce across 4 waves, then
  // one atomic per column into this block's slot (line-disjoint slots).
#pragma unroll
  for (int i = 0; i < 8; i++) {
    ss[i] += __shfl_xor(ss[i], 32);
    sq[i] += __shfl_xor(sq[i], 32);
  }
  __shared__ float red[2][4][64];
  const int wv = tid >> 6;
  if (lane < 8) {
#pragma unroll
    for (int i = 0; i < 8; i++) {
      red[0][wv][8 * cl + i] = ss[i];
      red[1][wv][8 * cl + i] = sq[i];
    }
  }
  __syncthreads();
  if (tid < 128) {
    int s = tid >> 6, c = tid & 63;
    float v = red[s][0][c] + red[s][1][c] + red[s][2][c] + red[s][3][c];
    unsafeAtomicAdd(&statsP[(blockIdx.x & (NSLOT - 1)) * 128 + s * 64 + c], v);
  }
}

// ---------------- layer-3 apply fused with mean-pool (batch sorted) ---------
// BN params recomputed inline from the 32 stat slots.
__global__ __launch_bounds__(256) void k_apply_pool(const float* __restrict__ agg,
                                                    const float* __restrict__ stats,
                                                    const float* __restrict__ gam,
                                                    const float* __restrict__ bet,
                                                    const int* __restrict__ batch,
                                                    float* __restrict__ pool,
                                                    float* __restrict__ cnt) {
  const int lane = threadIdx.x & 63;
  const int wave = blockIdx.x * 4 + (threadIdx.x >> 6);
  const int nwaves = gridDim.x * 4;
  const int chunk = (NN + nwaves - 1) / nwaves;
  int r0 = wave * chunk;
  int r1 = min(r0 + chunk, NN);
  if (r0 >= r1) return;
  const float inv_n = 1.0f / NN;
  float ssum = 0.f, ssq = 0.f;
  for (int sl = 0; sl < NSLOT; sl++) {
    ssum += stats[sl * 128 + lane];
    ssq += stats[sl * 128 + 64 + lane];
  }
  const float mean = ssum * inv_n;
  const float var = ssq * inv_n - mean * mean;
  const float sc = gam[lane] * rsqrtf(var + 1e-5f);
  const float sh = bet[lane] - mean * sc;
  int cur = batch[r0];
  float acc = 0.f, runlen = 0.f;
#pragma unroll 1
  for (int r = r0; r < r1; r++) {
    int g = batch[r];
    if (g != cur) {
      unsafeAtomicAdd(&pool[cur * 64 + lane], acc);
      if (lane == 0) unsafeAtomicAdd(&cnt[cur], runlen);
      acc = 0.f; runlen = 0.f; cur = g;
    }
    acc += fmaxf(agg[(size_t)r * 64 + lane] * sc + sh, 0.f);
    runlen += 1.f;
  }
  unsafeAtomicAdd(&pool[cur * 64 + lane], acc);
  if (lane == 0) unsafeAtomicAdd(&cnt[cur], runlen);
}

__global__ void k_finalize(const float* __restrict__ pool, const float* __restrict__ cnt,
                           float* __restrict__ out) {
  int i = blockIdx.x * 256 + threadIdx.x;
  if (i < NG * 64) out[i] = pool[i] / fmaxf(cnt[i >> 6], 1.0f);
}

extern "C" void kernel_launch(void* const* d_in, const int* in_sizes, int n_in,
                              void* d_out, int out_size, void* d_ws, size_t ws_size,
                              hipStream_t stream) {
  const float* x = (const float*)d_in[0];
  const int* ei = (const int*)d_in[1];
  const int* batch = (const int*)d_in[3];
  const float* W1 = (const float*)d_in[4];
  const float* g1 = (const float*)d_in[6];
  const float* be1 = (const float*)d_in[7];
  const float* W2 = (const float*)d_in[8];
  const float* g2 = (const float*)d_in[10];
  const float* be2 = (const float*)d_in[11];
  const float* W3 = (const float*)d_in[12];
  const float* g3 = (const float*)d_in[14];
  const float* be3 = (const float*)d_in[15];
  float* out = (float*)d_out;

  char* ws = (char*)d_ws;
  float* agg = (float*)ws;      ws += (size_t)NN * 64 * 4;   // agg, row-major fp32
  __half* hq = (__half*)ws;     ws += (size_t)NN * 64 * 2;   // h*dinv, row-major fp16
  int* bpacked = (int*)ws;      ws += (size_t)NE * 4;
  int* edata = (int*)ws;        ws += (size_t)NE * 4;        // src only, dst-sorted
  int* rs = (int*)ws;           ws += 400016;                // (NN+1)*4 padded
  float* dinv = (float*)ws;     ws += (size_t)NN * 4;
  int* bcnt = (int*)ws;         ws += (size_t)NBUCK * NBLK * 4;
  int* boff = (int*)ws;         ws += (size_t)NBUCK * NBLK * 4;
  int* btot = (int*)ws;         ws += 512 * 4;
  int* bbase = (int*)ws;        ws += 512 * 4;
  float* statsP = (float*)ws;   ws += (size_t)3 * NSLOT * 128 * 4;  // slotted BN stats
  float* pool = (float*)ws;     ws += (size_t)NG * 64 * 4;
  float* cnt = (float*)ws;      ws += (size_t)NG * 4;
  __half* hWt = (__half*)ws;    ws += 32768;                 // W1t|W2t|W3t fp16

  // ---- CSR build: bucket sort (no global atomics, locality-bounded writes) --
  k_bhist<<<NBLK, 256, 0, stream>>>(ei, bcnt);
  k_scan1<<<NBUCK, 128, 0, stream>>>(bcnt, boff, btot);
  k_scan2<<<1, 512, 0, stream>>>(btot, bbase);
  k_bscatter<<<NBLK, 256, 0, stream>>>(ei, boff, bbase, bpacked);
  k_sortfill<<<NBUCK, 256, 0, stream>>>(bpacked, boff, bbase, dinv, rs, edata);
  k_wprep<<<64, 256, 0, stream>>>(W1, W2, W3, hWt, pool, cnt, statsP);

  const float* gs[3] = {g1, g2, g3};
  const float* bes[3] = {be1, be2, be3};
  const __half* Wts[3] = {hWt, hWt + 64 * 128, hWt + 64 * 128 + 64 * 64};

  for (int layer = 0; layer < 3; layer++) {
    if (layer == 0)
      k_gemm<128, false><<<1024, 256, 0, stream>>>(x, nullptr, nullptr, nullptr,
                                                   Wts[0], dinv, hq);
    else
      k_gemm<64, true><<<1024, 256, 0, stream>>>(agg, statsP + NSLOT * 128 * (layer - 1),
                                                 gs[layer - 1], bes[layer - 1],
                                                 Wts[layer], dinv, hq);
    k_gather<<<GGRID, 256, 0, stream>>>(hq, edata, rs, dinv, agg,
                                        statsP + NSLOT * 128 * layer);
    if (layer == 2) {
      k_apply_pool<<<1024, 256, 0, stream>>>(agg, statsP + NSLOT * 128 * 2, g3, be3,
                                             batch, pool, cnt);
      k_finalize<<<(NG * 64 + 255) / 256, 256, 0, stream>>>(pool, cnt, out);
    }
  }
}

// Round 9
// 482.531 us; speedup vs baseline: 1.0183x; 1.0183x over previous
//
#include <hip/hip_runtime.h>
#include <hip/hip_fp16.h>

constexpr int NN = 100000;   // nodes
constexpr int NE = 1600000;  // edges
constexpr int NG = 256;      // graphs
constexpr int NBUCK = 391;   // node buckets of 256 (391*256 = 100096 >= NN)
constexpr int NBLK = 128;    // blocks for bucket hist/scatter
constexpr int EPB = NE / NBLK;  // 12500 edges per block
constexpr int GGRID = 2048;  // gather grid (8 blocks/CU = 32 waves/CU)
constexpr int NSLOT = 32;    // BN-stat accumulator slots (line-disjoint)

typedef _Float16 f16x8 __attribute__((ext_vector_type(8)));
typedef float f32x4 __attribute__((ext_vector_type(4)));

// ===== CSR hist + W prep (fp16 transpose) + zero-inits, fused (1st kernel) ==
// hWt layout: W1t[64][128] | W2t[64][64] | W3t[64][64]
__global__ __launch_bounds__(256) void k_bhist(const int* __restrict__ ei,
                                               int* __restrict__ bcnt,
                                               const float* __restrict__ W1,
                                               const float* __restrict__ W2,
                                               const float* __restrict__ W3,
                                               __half* __restrict__ hWt,
                                               float* __restrict__ pool,
                                               float* __restrict__ cnt,
                                               float* __restrict__ statsP) {
  __shared__ int hc[NBUCK];
  int tid = threadIdx.x;
  for (int i = tid; i < NBUCK; i += 256) hc[i] = 0;
  __syncthreads();
  int e0 = blockIdx.x * EPB;
  for (int e = e0 + tid; e < e0 + EPB; e += 256) atomicAdd(&hc[ei[NE + e] >> 8], 1);
  // ---- independent prep work (hides behind the atomic traffic) ----
  int t = blockIdx.x * 256 + tid;
  int stride = gridDim.x * 256;
  for (int i = t; i < 128 * 64; i += stride) {
    int k = i >> 6, f = i & 63;
    hWt[f * 128 + k] = __float2half(W1[i]);
  }
  for (int i = t; i < 64 * 64; i += stride) {
    int k = i >> 6, f = i & 63;
    hWt[64 * 128 + f * 64 + k] = __float2half(W2[i]);
    hWt[64 * 128 + 64 * 64 + f * 64 + k] = __float2half(W3[i]);
  }
  for (int i = t; i < NG * 64; i += stride) pool[i] = 0.f;
  for (int i = t; i < NG; i += stride) cnt[i] = 0.f;
  for (int i = t; i < 3 * NSLOT * 128; i += stride) statsP[i] = 0.f;
  __syncthreads();
  for (int i = tid; i < NBUCK; i += 256) bcnt[i * NBLK + blockIdx.x] = hc[i];
}

// ---- hierarchical scan of bcnt[NBUCK][NBLK] -> boff (exclusive, LOCAL) ----
__global__ __launch_bounds__(128) void k_scan1(const int* __restrict__ bcnt,
                                               int* __restrict__ boff,
                                               int* __restrict__ btot) {
  __shared__ int s[128];
  int t = threadIdx.x, b = blockIdx.x;
  int v = bcnt[b * NBLK + t];
  s[t] = v;
  __syncthreads();
  for (int off = 1; off < 128; off <<= 1) {
    int x = (t >= off) ? s[t - off] : 0;
    __syncthreads();
    s[t] += x;
    __syncthreads();
  }
  boff[b * NBLK + t] = s[t] - v;  // local exclusive (bbase added at use site)
  if (t == 127) btot[b] = s[127];
}

__global__ __launch_bounds__(512) void k_scan2(const int* __restrict__ btot,
                                               int* __restrict__ bbase) {
  __shared__ int s[512];
  int t = threadIdx.x;
  int v = (t < NBUCK) ? btot[t] : 0;
  s[t] = v;
  __syncthreads();
  for (int off = 1; off < 512; off <<= 1) {
    int x = (t >= off) ? s[t - off] : 0;
    __syncthreads();
    s[t] += x;
    __syncthreads();
  }
  if (t < NBUCK) bbase[t] = s[t] - v;  // exclusive
}

// bbase[] folded in at read time (k_scan3 eliminated from the dispatch chain)
__global__ __launch_bounds__(256) void k_bscatter(const int* __restrict__ ei,
                                                  const int* __restrict__ boff,
                                                  const int* __restrict__ bbase,
                                                  int* __restrict__ bpacked) {
  __shared__ int cur[NBUCK];
  int tid = threadIdx.x;
  for (int i = tid; i < NBUCK; i += 256)
    cur[i] = boff[i * NBLK + blockIdx.x] + bbase[i];
  __syncthreads();
  int e0 = blockIdx.x * EPB;
  for (int e = e0 + tid; e < e0 + EPB; e += 256) {
    int s = ei[e], d = ei[NE + e];
    int pos = atomicAdd(&cur[d >> 8], 1);
    bpacked[pos] = s | ((d & 255) << 17);  // src fits 17 bits (NN < 131072)
  }
}

// Per bucket: hist -> deg/dinv, local scan -> rs, cursor fill -> edata (src).
__global__ __launch_bounds__(256) void k_sortfill(const int* __restrict__ bpacked,
                                                  const int* __restrict__ boff,
                                                  const int* __restrict__ bbase,
                                                  float* __restrict__ dinv,
                                                  int* __restrict__ rs,
                                                  int* __restrict__ edata) {
  __shared__ int hist[256], scn[256], cur[256];
  int tid = threadIdx.x, b = blockIdx.x;
  int bs = boff[b * NBLK] + bbase[b];
  int be = (b + 1 < NBUCK) ? boff[(b + 1) * NBLK] + bbase[b + 1] : NE;
  hist[tid] = 0;
  __syncthreads();
  for (int i = bs + tid; i < be; i += 256) atomicAdd(&hist[bpacked[i] >> 17], 1);
  __syncthreads();
  int n = (b << 8) + tid;
  int hv = hist[tid];
  if (n < NN) dinv[n] = rsqrtf((float)(hv + 1));  // +1 self-loop
  scn[tid] = hv;
  __syncthreads();
  for (int off = 1; off < 256; off <<= 1) {
    int v = (tid >= off) ? scn[tid - off] : 0;
    __syncthreads();
    scn[tid] += v;
    __syncthreads();
  }
  int excl = scn[tid] - hv;
  if (n < NN) rs[n] = bs + excl;
  if (b == NBUCK - 1 && tid == 0) rs[NN] = NE;
  cur[tid] = bs + excl;
  __syncthreads();
  for (int i = bs + tid; i < be; i += 256) {
    int p = bpacked[i];
    int pos = atomicAdd(&cur[p >> 17], 1);
    edata[pos] = p & 131071;  // writes confined to [bs,be) ~17KB window
  }
}

// ====== GEMM (MFMA fp16): hq[n][64] = fp16( (f(in)[N][K] @ W[K][64]) * dinv[n] )
// LDS-FREE: each lane's B-fragment is 8 CONSECUTIVE fp32 of its row — load them
// directly (2x float4 per K-chunk), BN+ReLU+cvt in registers, MFMA. BN sc/sh
// built once per block in LDS from the 32 stat slots.
// Swapped-operand MFMA: A = W^T, B = X. Lane mapping for BOTH operands:
// matrix index = lane&15, k = (lane>>4)*8 + j. D: col=lane&15 -> node,
// row -> feature 16t+4q+reg. NN/16 = 6250 exactly -> no row guards.
template <int K, bool BN>
__global__ __launch_bounds__(256) void k_gemm(const float* __restrict__ in,
                                              const float* __restrict__ stats,
                                              const float* __restrict__ gam,
                                              const float* __restrict__ bet,
                                              const __half* __restrict__ Wt,
                                              const float* __restrict__ dinv,
                                              __half* __restrict__ hq) {
  constexpr int KC = K / 32;       // K-chunks of 32
  const int tid = threadIdx.x;
  const int lane = tid & 63;
  const int wv = tid >> 6;
  const int q = lane >> 4;         // 0..3
  const int r15 = lane & 15;

  __shared__ float scs[64], shs[64];
  if (BN) {
    if (tid < 64) {
      const float inv_n = 1.0f / NN;
      float ssum = 0.f, ssq = 0.f;
      for (int sl = 0; sl < NSLOT; sl++) {
        ssum += stats[sl * 128 + tid];
        ssq += stats[sl * 128 + 64 + tid];
      }
      float mean = ssum * inv_n;
      float var = ssq * inv_n - mean * mean;
      float s = gam[tid] * rsqrtf(var + 1e-5f);
      scs[tid] = s;
      shs[tid] = bet[tid] - mean * s;
    }
    __syncthreads();
  }

  // ---- W fragments in registers: one 16B load each (fp16 pre-transposed) ----
  f16x8 wf[KC][4];
#pragma unroll
  for (int t = 0; t < 4; t++)
#pragma unroll
    for (int kc = 0; kc < KC; kc++)
      wf[kc][t] = *reinterpret_cast<const f16x8*>(Wt + (16 * t + r15) * K + kc * 32 + q * 8);

  // per-lane BN params for this lane's input columns (kc*32 + q*8 + j)
  float scr[KC][8], shr[KC][8];
  if (BN) {
#pragma unroll
    for (int kc = 0; kc < KC; kc++)
#pragma unroll
      for (int j = 0; j < 8; j++) {
        int col = kc * 32 + q * 8 + j;
        scr[kc][j] = scs[col];
        shr[kc][j] = shs[col];
      }
  }

  constexpr int tiles = NN / 16;   // 6250 exact
  const int gwave = blockIdx.x * 4 + wv;
  const int nw = gridDim.x * 4;
  for (int tile = gwave; tile < tiles; tile += nw) {
    const int node = tile * 16 + r15;
    const float* rowp = in + (size_t)node * K;
    f16x8 xf[KC];
#pragma unroll
    for (int kc = 0; kc < KC; kc++) {
      float4 a = *reinterpret_cast<const float4*>(rowp + kc * 32 + q * 8);
      float4 b = *reinterpret_cast<const float4*>(rowp + kc * 32 + q * 8 + 4);
      if (BN) {
        a.x = fmaxf(a.x * scr[kc][0] + shr[kc][0], 0.f);
        a.y = fmaxf(a.y * scr[kc][1] + shr[kc][1], 0.f);
        a.z = fmaxf(a.z * scr[kc][2] + shr[kc][2], 0.f);
        a.w = fmaxf(a.w * scr[kc][3] + shr[kc][3], 0.f);
        b.x = fmaxf(b.x * scr[kc][4] + shr[kc][4], 0.f);
        b.y = fmaxf(b.y * scr[kc][5] + shr[kc][5], 0.f);
        b.z = fmaxf(b.z * scr[kc][6] + shr[kc][6], 0.f);
        b.w = fmaxf(b.w * scr[kc][7] + shr[kc][7], 0.f);
      }
      f16x8 x;
      x[0] = (_Float16)a.x; x[1] = (_Float16)a.y;
      x[2] = (_Float16)a.z; x[3] = (_Float16)a.w;
      x[4] = (_Float16)b.x; x[5] = (_Float16)b.y;
      x[6] = (_Float16)b.z; x[7] = (_Float16)b.w;
      xf[kc] = x;
    }

    f32x4 acc[4] = {f32x4{0.f, 0.f, 0.f, 0.f}, f32x4{0.f, 0.f, 0.f, 0.f},
                    f32x4{0.f, 0.f, 0.f, 0.f}, f32x4{0.f, 0.f, 0.f, 0.f}};
#pragma unroll
    for (int kc = 0; kc < KC; kc++)
#pragma unroll
      for (int t = 0; t < 4; t++)
        acc[t] = __builtin_amdgcn_mfma_f32_16x16x32_f16(wf[kc][t], xf[kc], acc[t], 0, 0, 0);

    const float dv = dinv[node];
#pragma unroll
    for (int t = 0; t < 4; t++) {
      union {
        __half2 h2[2];
        float2 f2;
      } u;
      u.h2[0] = __floats2half2_rn(acc[t][0] * dv, acc[t][1] * dv);
      u.h2[1] = __floats2half2_rn(acc[t][2] * dv, acc[t][3] * dv);
      *reinterpret_cast<float2*>(hq + (size_t)node * 64 + 16 * t + 4 * q) = u.f2;
    }
  }
}

// ====== Gather: agg[d] = dinv[d] * (sum_src h'[src] + h'[d]) ================
// h' = h*dinv (fp16, 128 B row). Wave = 2 nodes (lane<32: even, >=32: odd);
// per half: 4 streams of 8 lanes, lane owns 8 cols (16 B float4 = full row per
// 8-lane group). 2-deep unroll (r2-proven core). edata uses nontemporal LOADS
// (streamed once; keeps L2 for hq). agg uses PLAIN stores — it is re-read by
// the next gemm/apply_pool, so nt-store evicts lines the consumer needs (r8
// regression, reverted). BN stats: LDS-reduce, one atomic/col into slot
// blockIdx&31 (line-disjoint).
__global__ __launch_bounds__(256) void k_gather(const __half* __restrict__ hq,
                                                const int* __restrict__ edata,
                                                const int* __restrict__ rs,
                                                const float* __restrict__ dinv,
                                                float* __restrict__ agg,
                                                float* __restrict__ statsP) {
  const int tid = threadIdx.x;
  const int lane = tid & 63;
  const int half = lane >> 5;      // 0: even node, 1: odd node
  const int hs = (lane >> 3) & 3;  // stream within half (0..3)
  const int cl = lane & 7;         // col group: cols 8*cl..8*cl+7 (16 B)
  const int wave = blockIdx.x * 4 + (tid >> 6);
  const int nwaves = GGRID * 4;
  float ss[8] = {0.f, 0.f, 0.f, 0.f, 0.f, 0.f, 0.f, 0.f};
  float sq[8] = {0.f, 0.f, 0.f, 0.f, 0.f, 0.f, 0.f, 0.f};
  constexpr int NPAIR = NN / 2;
#pragma unroll 1
  for (int pr = wave; pr < NPAIR; pr += nwaves) {
    const int node = 2 * pr + half;
    int e0 = rs[node], e1 = rs[node + 1];
    float a[8] = {0.f, 0.f, 0.f, 0.f, 0.f, 0.f, 0.f, 0.f};
    int e = e0 + hs;
#pragma unroll 1
    for (; e + 4 < e1; e += 8) {  // 2 edges per stream in flight
      int s0 = __builtin_nontemporal_load(edata + e);
      int s1 = __builtin_nontemporal_load(edata + e + 4);
      float4 r0 = ((const float4*)(hq + (size_t)s0 * 64))[cl];
      float4 r1 = ((const float4*)(hq + (size_t)s1 * 64))[cl];
      const __half2* h0 = (const __half2*)&r0;
      const __half2* h1 = (const __half2*)&r1;
#pragma unroll
      for (int i = 0; i < 4; i++) {
        float2 f = __half22float2(h0[i]);
        float2 g = __half22float2(h1[i]);
        a[2 * i] += f.x + g.x;
        a[2 * i + 1] += f.y + g.y;
      }
    }
    if (e < e1) {
      int s0 = __builtin_nontemporal_load(edata + e);
      float4 r0 = ((const float4*)(hq + (size_t)s0 * 64))[cl];
      const __half2* h0 = (const __half2*)&r0;
#pragma unroll
      for (int i = 0; i < 4; i++) {
        float2 f = __half22float2(h0[i]);
        a[2 * i] += f.x;
        a[2 * i + 1] += f.y;
      }
    }
    // combine the 4 streams of each half (2 levels; halves stay independent)
#pragma unroll
    for (int i = 0; i < 8; i++) {
      a[i] += __shfl_xor(a[i], 8);
      a[i] += __shfl_xor(a[i], 16);
    }
    if (hs == 0) {
      // self term + final scale by dinv[node]
      float4 rsv = ((const float4*)(hq + (size_t)node * 64))[cl];
      const __half2* hsv = (const __half2*)&rsv;
      float dv = dinv[node];
      float o[8];
#pragma unroll
      for (int i = 0; i < 4; i++) {
        float2 f = __half22float2(hsv[i]);
        o[2 * i] = (a[2 * i] + f.x) * dv;
        o[2 * i + 1] = (a[2 * i + 1] + f.y) * dv;
      }
      float4 o0 = {o[0], o[1], o[2], o[3]};
      float4 o1 = {o[4], o[5], o[6], o[7]};
      ((float4*)(agg + (size_t)node * 64))[2 * cl] = o0;
      ((float4*)(agg + (size_t)node * 64))[2 * cl + 1] = o1;
#pragma unroll
      for (int i = 0; i < 8; i++) {
        ss[i] += o[i];
        sq[i] += o[i] * o[i];
      }
    }
  }
  // fold odd-node-half stats into lanes 0-7, LDS-reduce across 4 waves, then
  // one atomic per column into this block's slot (line-disjoint slots).
#pragma unroll
  for (int i = 0; i < 8; i++) {
    ss[i] += __shfl_xor(ss[i], 32);
    sq[i] += __shfl_xor(sq[i], 32);
  }
  __shared__ float red[2][4][64];
  const int wv = tid >> 6;
  if (lane < 8) {
#pragma unroll
    for (int i = 0; i < 8; i++) {
      red[0][wv][8 * cl + i] = ss[i];
      red[1][wv][8 * cl + i] = sq[i];
    }
  }
  __syncthreads();
  if (tid < 128) {
    int s = tid >> 6, c = tid & 63;
    float v = red[s][0][c] + red[s][1][c] + red[s][2][c] + red[s][3][c];
    unsafeAtomicAdd(&statsP[(blockIdx.x & (NSLOT - 1)) * 128 + s * 64 + c], v);
  }
}

// ---------------- layer-3 apply fused with mean-pool (batch sorted) ---------
// BN params recomputed inline from the 32 stat slots.
__global__ __launch_bounds__(256) void k_apply_pool(const float* __restrict__ agg,
                                                    const float* __restrict__ stats,
                                                    const float* __restrict__ gam,
                                                    const float* __restrict__ bet,
                                                    const int* __restrict__ batch,
                                                    float* __restrict__ pool,
                                                    float* __restrict__ cnt) {
  const int lane = threadIdx.x & 63;
  const int wave = blockIdx.x * 4 + (threadIdx.x >> 6);
  const int nwaves = gridDim.x * 4;
  const int chunk = (NN + nwaves - 1) / nwaves;
  int r0 = wave * chunk;
  int r1 = min(r0 + chunk, NN);
  if (r0 >= r1) return;
  const float inv_n = 1.0f / NN;
  float ssum = 0.f, ssq = 0.f;
  for (int sl = 0; sl < NSLOT; sl++) {
    ssum += stats[sl * 128 + lane];
    ssq += stats[sl * 128 + 64 + lane];
  }
  const float mean = ssum * inv_n;
  const float var = ssq * inv_n - mean * mean;
  const float sc = gam[lane] * rsqrtf(var + 1e-5f);
  const float sh = bet[lane] - mean * sc;
  int cur = batch[r0];
  float acc = 0.f, runlen = 0.f;
#pragma unroll 1
  for (int r = r0; r < r1; r++) {
    int g = batch[r];
    if (g != cur) {
      unsafeAtomicAdd(&pool[cur * 64 + lane], acc);
      if (lane == 0) unsafeAtomicAdd(&cnt[cur], runlen);
      acc = 0.f; runlen = 0.f; cur = g;
    }
    acc += fmaxf(agg[(size_t)r * 64 + lane] * sc + sh, 0.f);
    runlen += 1.f;
  }
  unsafeAtomicAdd(&pool[cur * 64 + lane], acc);
  if (lane == 0) unsafeAtomicAdd(&cnt[cur], runlen);
}

__global__ void k_finalize(const float* __restrict__ pool, const float* __restrict__ cnt,
                           float* __restrict__ out) {
  int i = blockIdx.x * 256 + threadIdx.x;
  if (i < NG * 64) out[i] = pool[i] / fmaxf(cnt[i >> 6], 1.0f);
}

extern "C" void kernel_launch(void* const* d_in, const int* in_sizes, int n_in,
                              void* d_out, int out_size, void* d_ws, size_t ws_size,
                              hipStream_t stream) {
  const float* x = (const float*)d_in[0];
  const int* ei = (const int*)d_in[1];
  const int* batch = (const int*)d_in[3];
  const float* W1 = (const float*)d_in[4];
  const float* g1 = (const float*)d_in[6];
  const float* be1 = (const float*)d_in[7];
  const float* W2 = (const float*)d_in[8];
  const float* g2 = (const float*)d_in[10];
  const float* be2 = (const float*)d_in[11];
  const float* W3 = (const float*)d_in[12];
  const float* g3 = (const float*)d_in[14];
  const float* be3 = (const float*)d_in[15];
  float* out = (float*)d_out;

  char* ws = (char*)d_ws;
  float* agg = (float*)ws;      ws += (size_t)NN * 64 * 4;   // agg, row-major fp32
  __half* hq = (__half*)ws;     ws += (size_t)NN * 64 * 2;   // h*dinv, row-major fp16
  int* bpacked = (int*)ws;      ws += (size_t)NE * 4;
  int* edata = (int*)ws;        ws += (size_t)NE * 4;        // src only, dst-sorted
  int* rs = (int*)ws;           ws += 400016;                // (NN+1)*4 padded
  float* dinv = (float*)ws;     ws += (size_t)NN * 4;
  int* bcnt = (int*)ws;         ws += (size_t)NBUCK * NBLK * 4;
  int* boff = (int*)ws;         ws += (size_t)NBUCK * NBLK * 4;
  int* btot = (int*)ws;         ws += 512 * 4;
  int* bbase = (int*)ws;        ws += 512 * 4;
  float* statsP = (float*)ws;   ws += (size_t)3 * NSLOT * 128 * 4;  // slotted BN stats
  float* pool = (float*)ws;     ws += (size_t)NG * 64 * 4;
  float* cnt = (float*)ws;      ws += (size_t)NG * 4;
  __half* hWt = (__half*)ws;    ws += 32768;                 // W1t|W2t|W3t fp16

  // ---- CSR build (W-prep + zero-inits fused into the first kernel) ----
  k_bhist<<<NBLK, 256, 0, stream>>>(ei, bcnt, W1, W2, W3, hWt, pool, cnt, statsP);
  k_scan1<<<NBUCK, 128, 0, stream>>>(bcnt, boff, btot);
  k_scan2<<<1, 512, 0, stream>>>(btot, bbase);
  k_bscatter<<<NBLK, 256, 0, stream>>>(ei, boff, bbase, bpacked);
  k_sortfill<<<NBUCK, 256, 0, stream>>>(bpacked, boff, bbase, dinv, rs, edata);

  const float* gs[3] = {g1, g2, g3};
  const float* bes[3] = {be1, be2, be3};
  const __half* Wts[3] = {hWt, hWt + 64 * 128, hWt + 64 * 128 + 64 * 64};

  for (int layer = 0; layer < 3; layer++) {
    if (layer == 0)
      k_gemm<128, false><<<1024, 256, 0, stream>>>(x, nullptr, nullptr, nullptr,
                                                   Wts[0], dinv, hq);
    else
      k_gemm<64, true><<<1024, 256, 0, stream>>>(agg, statsP + NSLOT * 128 * (layer - 1),
                                                 gs[layer - 1], bes[layer - 1],
                                                 Wts[layer], dinv, hq);
    k_gather<<<GGRID, 256, 0, stream>>>(hq, edata, rs, dinv, agg,
                                        statsP + NSLOT * 128 * layer);
    if (layer == 2) {
      k_apply_pool<<<1024, 256, 0, stream>>>(agg, statsP + NSLOT * 128 * 2, g3, be3,
                                             batch, pool, cnt);
      k_finalize<<<(NG * 64 + 255) / 256, 256, 0, stream>>>(pool, cnt, out);
    }
  }
}

// Round 11
// 462.372 us; speedup vs baseline: 1.0627x; 1.0436x over previous
//
#include <hip/hip_runtime.h>
#include <hip/hip_fp16.h>

constexpr int NN = 100000;   // nodes
constexpr int NE = 1600000;  // edges
constexpr int NG = 256;      // graphs
constexpr int NBUCK = 391;   // node buckets of 256 (391*256 = 100096 >= NN)
constexpr int NBLK = 256;    // blocks for bucket hist/scatter (full CU set)
constexpr int EPB = NE / NBLK;  // 6250 edges per block
constexpr int GGRID = 2048;  // gather grid (8 blocks/CU = 32 waves/CU)
constexpr int NSLOT = 32;    // BN-stat accumulator slots (line-disjoint)

typedef _Float16 f16x8 __attribute__((ext_vector_type(8)));
typedef float f32x4 __attribute__((ext_vector_type(4)));

// ===== CSR hist + W prep (fp16 transpose) + zero-inits, fused (1st kernel) ==
// hWt layout: W1t[64][128] | W2t[64][64] | W3t[64][64]
__global__ __launch_bounds__(256) void k_bhist(const int* __restrict__ ei,
                                               int* __restrict__ bcnt,
                                               const float* __restrict__ W1,
                                               const float* __restrict__ W2,
                                               const float* __restrict__ W3,
                                               __half* __restrict__ hWt,
                                               float* __restrict__ pool,
                                               float* __restrict__ cnt,
                                               float* __restrict__ statsP) {
  __shared__ int hc[NBUCK];
  int tid = threadIdx.x;
  for (int i = tid; i < NBUCK; i += 256) hc[i] = 0;
  __syncthreads();
  int e0 = blockIdx.x * EPB;
  for (int e = e0 + tid; e < e0 + EPB; e += 256) atomicAdd(&hc[ei[NE + e] >> 8], 1);
  // ---- independent prep work (hides behind the atomic traffic) ----
  int t = blockIdx.x * 256 + tid;
  int stride = gridDim.x * 256;
  for (int i = t; i < 128 * 64; i += stride) {
    int k = i >> 6, f = i & 63;
    hWt[f * 128 + k] = __float2half(W1[i]);
  }
  for (int i = t; i < 64 * 64; i += stride) {
    int k = i >> 6, f = i & 63;
    hWt[64 * 128 + f * 64 + k] = __float2half(W2[i]);
    hWt[64 * 128 + 64 * 64 + f * 64 + k] = __float2half(W3[i]);
  }
  for (int i = t; i < NG * 64; i += stride) pool[i] = 0.f;
  for (int i = t; i < NG; i += stride) cnt[i] = 0.f;
  for (int i = t; i < 3 * NSLOT * 128; i += stride) statsP[i] = 0.f;
  __syncthreads();
  for (int i = tid; i < NBUCK; i += 256) bcnt[i * NBLK + blockIdx.x] = hc[i];
}

// ---- hierarchical scan of bcnt[NBUCK][NBLK] -> boff (exclusive, LOCAL) ----
__global__ __launch_bounds__(NBLK) void k_scan1(const int* __restrict__ bcnt,
                                                int* __restrict__ boff,
                                                int* __restrict__ btot) {
  __shared__ int s[NBLK];
  int t = threadIdx.x, b = blockIdx.x;
  int v = bcnt[b * NBLK + t];
  s[t] = v;
  __syncthreads();
  for (int off = 1; off < NBLK; off <<= 1) {
    int x = (t >= off) ? s[t - off] : 0;
    __syncthreads();
    s[t] += x;
    __syncthreads();
  }
  boff[b * NBLK + t] = s[t] - v;  // local exclusive (bbase added at use site)
  if (t == NBLK - 1) btot[b] = s[NBLK - 1];
}

__global__ __launch_bounds__(512) void k_scan2(const int* __restrict__ btot,
                                               int* __restrict__ bbase) {
  __shared__ int s[512];
  int t = threadIdx.x;
  int v = (t < NBUCK) ? btot[t] : 0;
  s[t] = v;
  __syncthreads();
  for (int off = 1; off < 512; off <<= 1) {
    int x = (t >= off) ? s[t - off] : 0;
    __syncthreads();
    s[t] += x;
    __syncthreads();
  }
  if (t < NBUCK) bbase[t] = s[t] - v;  // exclusive
}

// bbase[] folded in at read time (k_scan3 eliminated from the dispatch chain)
__global__ __launch_bounds__(256) void k_bscatter(const int* __restrict__ ei,
                                                  const int* __restrict__ boff,
                                                  const int* __restrict__ bbase,
                                                  int* __restrict__ bpacked) {
  __shared__ int cur[NBUCK];
  int tid = threadIdx.x;
  for (int i = tid; i < NBUCK; i += 256)
    cur[i] = boff[i * NBLK + blockIdx.x] + bbase[i];
  __syncthreads();
  int e0 = blockIdx.x * EPB;
  for (int e = e0 + tid; e < e0 + EPB; e += 256) {
    int s = ei[e], d = ei[NE + e];
    int pos = atomicAdd(&cur[d >> 8], 1);
    bpacked[pos] = s | ((d & 255) << 17);  // src fits 17 bits (NN < 131072)
  }
}

// Per bucket: hist -> deg/dinv, local scan -> rs, cursor fill -> edata (src).
__global__ __launch_bounds__(256) void k_sortfill(const int* __restrict__ bpacked,
                                                  const int* __restrict__ boff,
                                                  const int* __restrict__ bbase,
                                                  float* __restrict__ dinv,
                                                  int* __restrict__ rs,
                                                  int* __restrict__ edata) {
  __shared__ int hist[256], scn[256], cur[256];
  int tid = threadIdx.x, b = blockIdx.x;
  int bs = boff[b * NBLK] + bbase[b];
  int be = (b + 1 < NBUCK) ? boff[(b + 1) * NBLK] + bbase[b + 1] : NE;
  hist[tid] = 0;
  __syncthreads();
  for (int i = bs + tid; i < be; i += 256) atomicAdd(&hist[bpacked[i] >> 17], 1);
  __syncthreads();
  int n = (b << 8) + tid;
  int hv = hist[tid];
  if (n < NN) dinv[n] = rsqrtf((float)(hv + 1));  // +1 self-loop
  scn[tid] = hv;
  __syncthreads();
  for (int off = 1; off < 256; off <<= 1) {
    int v = (tid >= off) ? scn[tid - off] : 0;
    __syncthreads();
    scn[tid] += v;
    __syncthreads();
  }
  int excl = scn[tid] - hv;
  if (n < NN) rs[n] = bs + excl;
  if (b == NBUCK - 1 && tid == 0) rs[NN] = NE;
  cur[tid] = bs + excl;
  __syncthreads();
  for (int i = bs + tid; i < be; i += 256) {
    int p = bpacked[i];
    int pos = atomicAdd(&cur[p >> 17], 1);
    edata[pos] = p & 131071;  // writes confined to [bs,be) ~17KB window
  }
}

// ====== GEMM (MFMA fp16): hq[n][64] = fp16( (f(in)[N][K] @ W[K][64]) * dinv[n] )
// LDS-FREE: each lane's B-fragment is 8 CONSECUTIVE fp32 of its row — load them
// directly (2x float4 per K-chunk), BN+ReLU+cvt in registers, MFMA. BN sc/sh
// built once per block in LDS from the 32 stat slots.
// Swapped-operand MFMA: A = W^T, B = X. Lane mapping for BOTH operands:
// matrix index = lane&15, k = (lane>>4)*8 + j. D: col=lane&15 -> node,
// row -> feature 16t+4q+reg. NN/16 = 6250 exactly -> no row guards.
template <int K, bool BN>
__global__ __launch_bounds__(256) void k_gemm(const float* __restrict__ in,
                                              const float* __restrict__ stats,
                                              const float* __restrict__ gam,
                                              const float* __restrict__ bet,
                                              const __half* __restrict__ Wt,
                                              const float* __restrict__ dinv,
                                              __half* __restrict__ hq) {
  constexpr int KC = K / 32;       // K-chunks of 32
  const int tid = threadIdx.x;
  const int lane = tid & 63;
  const int wv = tid >> 6;
  const int q = lane >> 4;         // 0..3
  const int r15 = lane & 15;

  __shared__ float scs[64], shs[64];
  if (BN) {
    if (tid < 64) {
      const float inv_n = 1.0f / NN;
      float ssum = 0.f, ssq = 0.f;
      for (int sl = 0; sl < NSLOT; sl++) {
        ssum += stats[sl * 128 + tid];
        ssq += stats[sl * 128 + 64 + tid];
      }
      float mean = ssum * inv_n;
      float var = ssq * inv_n - mean * mean;
      float s = gam[tid] * rsqrtf(var + 1e-5f);
      scs[tid] = s;
      shs[tid] = bet[tid] - mean * s;
    }
    __syncthreads();
  }

  // ---- W fragments in registers: one 16B load each (fp16 pre-transposed) ----
  f16x8 wf[KC][4];
#pragma unroll
  for (int t = 0; t < 4; t++)
#pragma unroll
    for (int kc = 0; kc < KC; kc++)
      wf[kc][t] = *reinterpret_cast<const f16x8*>(Wt + (16 * t + r15) * K + kc * 32 + q * 8);

  // per-lane BN params for this lane's input columns (kc*32 + q*8 + j)
  float scr[KC][8], shr[KC][8];
  if (BN) {
#pragma unroll
    for (int kc = 0; kc < KC; kc++)
#pragma unroll
      for (int j = 0; j < 8; j++) {
        int col = kc * 32 + q * 8 + j;
        scr[kc][j] = scs[col];
        shr[kc][j] = shs[col];
      }
  }

  constexpr int tiles = NN / 16;   // 6250 exact
  const int gwave = blockIdx.x * 4 + wv;
  const int nw = gridDim.x * 4;
  for (int tile = gwave; tile < tiles; tile += nw) {
    const int node = tile * 16 + r15;
    const float* rowp = in + (size_t)node * K;
    f16x8 xf[KC];
#pragma unroll
    for (int kc = 0; kc < KC; kc++) {
      float4 a = *reinterpret_cast<const float4*>(rowp + kc * 32 + q * 8);
      float4 b = *reinterpret_cast<const float4*>(rowp + kc * 32 + q * 8 + 4);
      if (BN) {
        a.x = fmaxf(a.x * scr[kc][0] + shr[kc][0], 0.f);
        a.y = fmaxf(a.y * scr[kc][1] + shr[kc][1], 0.f);
        a.z = fmaxf(a.z * scr[kc][2] + shr[kc][2], 0.f);
        a.w = fmaxf(a.w * scr[kc][3] + shr[kc][3], 0.f);
        b.x = fmaxf(b.x * scr[kc][4] + shr[kc][4], 0.f);
        b.y = fmaxf(b.y * scr[kc][5] + shr[kc][5], 0.f);
        b.z = fmaxf(b.z * scr[kc][6] + shr[kc][6], 0.f);
        b.w = fmaxf(b.w * scr[kc][7] + shr[kc][7], 0.f);
      }
      f16x8 x;
      x[0] = (_Float16)a.x; x[1] = (_Float16)a.y;
      x[2] = (_Float16)a.z; x[3] = (_Float16)a.w;
      x[4] = (_Float16)b.x; x[5] = (_Float16)b.y;
      x[6] = (_Float16)b.z; x[7] = (_Float16)b.w;
      xf[kc] = x;
    }

    f32x4 acc[4] = {f32x4{0.f, 0.f, 0.f, 0.f}, f32x4{0.f, 0.f, 0.f, 0.f},
                    f32x4{0.f, 0.f, 0.f, 0.f}, f32x4{0.f, 0.f, 0.f, 0.f}};
#pragma unroll
    for (int kc = 0; kc < KC; kc++)
#pragma unroll
      for (int t = 0; t < 4; t++)
        acc[t] = __builtin_amdgcn_mfma_f32_16x16x32_f16(wf[kc][t], xf[kc], acc[t], 0, 0, 0);

    const float dv = dinv[node];
#pragma unroll
    for (int t = 0; t < 4; t++) {
      union {
        __half2 h2[2];
        float2 f2;
      } u;
      u.h2[0] = __floats2half2_rn(acc[t][0] * dv, acc[t][1] * dv);
      u.h2[1] = __floats2half2_rn(acc[t][2] * dv, acc[t][3] * dv);
      *reinterpret_cast<float2*>(hq + (size_t)node * 64 + 16 * t + 4 * q) = u.f2;
    }
  }
}

// ====== Gather: agg[d] = dinv[d] * (sum_src h'[src] + h'[d]) ================
// h' = h*dinv (fp16, 128 B row). Wave = 2 nodes (lane<32: even, >=32: odd);
// per half: 4 streams of 8 lanes, lane owns 8 cols (16 B float4 = full row per
// 8-lane group). 2-deep unroll (r2-proven core). edata uses nontemporal LOADS
// (streamed once; keeps L2 for hq). agg uses PLAIN stores — re-read by the
// next gemm/apply_pool (nt-store was the r8 regression). BN stats: LDS-reduce,
// one atomic/col into slot blockIdx&31 (line-disjoint).
__global__ __launch_bounds__(256) void k_gather(const __half* __restrict__ hq,
                                                const int* __restrict__ edata,
                                                const int* __restrict__ rs,
                                                const float* __restrict__ dinv,
                                                float* __restrict__ agg,
                                                float* __restrict__ statsP) {
  const int tid = threadIdx.x;
  const int lane = tid & 63;
  const int half = lane >> 5;      // 0: even node, 1: odd node
  const int hs = (lane >> 3) & 3;  // stream within half (0..3)
  const int cl = lane & 7;         // col group: cols 8*cl..8*cl+7 (16 B)
  const int wave = blockIdx.x * 4 + (tid >> 6);
  const int nwaves = GGRID * 4;
  float ss[8] = {0.f, 0.f, 0.f, 0.f, 0.f, 0.f, 0.f, 0.f};
  float sq[8] = {0.f, 0.f, 0.f, 0.f, 0.f, 0.f, 0.f, 0.f};
  constexpr int NPAIR = NN / 2;
#pragma unroll 1
  for (int pr = wave; pr < NPAIR; pr += nwaves) {
    const int node = 2 * pr + half;
    int e0 = rs[node], e1 = rs[node + 1];
    float a[8] = {0.f, 0.f, 0.f, 0.f, 0.f, 0.f, 0.f, 0.f};
    int e = e0 + hs;
#pragma unroll 1
    for (; e + 4 < e1; e += 8) {  // 2 edges per stream in flight
      int s0 = __builtin_nontemporal_load(edata + e);
      int s1 = __builtin_nontemporal_load(edata + e + 4);
      float4 r0 = ((const float4*)(hq + (size_t)s0 * 64))[cl];
      float4 r1 = ((const float4*)(hq + (size_t)s1 * 64))[cl];
      const __half2* h0 = (const __half2*)&r0;
      const __half2* h1 = (const __half2*)&r1;
#pragma unroll
      for (int i = 0; i < 4; i++) {
        float2 f = __half22float2(h0[i]);
        float2 g = __half22float2(h1[i]);
        a[2 * i] += f.x + g.x;
        a[2 * i + 1] += f.y + g.y;
      }
    }
    if (e < e1) {
      int s0 = __builtin_nontemporal_load(edata + e);
      float4 r0 = ((const float4*)(hq + (size_t)s0 * 64))[cl];
      const __half2* h0 = (const __half2*)&r0;
#pragma unroll
      for (int i = 0; i < 4; i++) {
        float2 f = __half22float2(h0[i]);
        a[2 * i] += f.x;
        a[2 * i + 1] += f.y;
      }
    }
    // combine the 4 streams of each half (2 levels; halves stay independent)
#pragma unroll
    for (int i = 0; i < 8; i++) {
      a[i] += __shfl_xor(a[i], 8);
      a[i] += __shfl_xor(a[i], 16);
    }
    if (hs == 0) {
      // self term + final scale by dinv[node]
      float4 rsv = ((const float4*)(hq + (size_t)node * 64))[cl];
      const __half2* hsv = (const __half2*)&rsv;
      float dv = dinv[node];
      float o[8];
#pragma unroll
      for (int i = 0; i < 4; i++) {
        float2 f = __half22float2(hsv[i]);
        o[2 * i] = (a[2 * i] + f.x) * dv;
        o[2 * i + 1] = (a[2 * i + 1] + f.y) * dv;
      }
      float4 o0 = {o[0], o[1], o[2], o[3]};
      float4 o1 = {o[4], o[5], o[6], o[7]};
      ((float4*)(agg + (size_t)node * 64))[2 * cl] = o0;
      ((float4*)(agg + (size_t)node * 64))[2 * cl + 1] = o1;
#pragma unroll
      for (int i = 0; i < 8; i++) {
        ss[i] += o[i];
        sq[i] += o[i] * o[i];
      }
    }
  }
  // fold odd-node-half stats into lanes 0-7, LDS-reduce across 4 waves, then
  // one atomic per column into this block's slot (line-disjoint slots).
#pragma unroll
  for (int i = 0; i < 8; i++) {
    ss[i] += __shfl_xor(ss[i], 32);
    sq[i] += __shfl_xor(sq[i], 32);
  }
  __shared__ float red[2][4][64];
  const int wv = tid >> 6;
  if (lane < 8) {
#pragma unroll
    for (int i = 0; i < 8; i++) {
      red[0][wv][8 * cl + i] = ss[i];
      red[1][wv][8 * cl + i] = sq[i];
    }
  }
  __syncthreads();
  if (tid < 128) {
    int s = tid >> 6, c = tid & 63;
    float v = red[s][0][c] + red[s][1][c] + red[s][2][c] + red[s][3][c];
    unsafeAtomicAdd(&statsP[(blockIdx.x & (NSLOT - 1)) * 128 + s * 64 + c], v);
  }
}

// ---------------- layer-3 apply fused with mean-pool (batch sorted) ---------
// BN params recomputed inline from the 32 stat slots.
__global__ __launch_bounds__(256) void k_apply_pool(const float* __restrict__ agg,
                                                    const float* __restrict__ stats,
                                                    const float* __restrict__ gam,
                                                    const float* __restrict__ bet,
                                                    const int* __restrict__ batch,
                                                    float* __restrict__ pool,
                                                    float* __restrict__ cnt) {
  const int lane = threadIdx.x & 63;
  const int wave = blockIdx.x * 4 + (threadIdx.x >> 6);
  const int nwaves = gridDim.x * 4;
  const int chunk = (NN + nwaves - 1) / nwaves;
  int r0 = wave * chunk;
  int r1 = min(r0 + chunk, NN);
  if (r0 >= r1) return;
  const float inv_n = 1.0f / NN;
  float ssum = 0.f, ssq = 0.f;
  for (int sl = 0; sl < NSLOT; sl++) {
    ssum += stats[sl * 128 + lane];
    ssq += stats[sl * 128 + 64 + lane];
  }
  const float mean = ssum * inv_n;
  const float var = ssq * inv_n - mean * mean;
  const float sc = gam[lane] * rsqrtf(var + 1e-5f);
  const float sh = bet[lane] - mean * sc;
  int cur = batch[r0];
  float acc = 0.f, runlen = 0.f;
#pragma unroll 1
  for (int r = r0; r < r1; r++) {
    int g = batch[r];
    if (g != cur) {
      unsafeAtomicAdd(&pool[cur * 64 + lane], acc);
      if (lane == 0) unsafeAtomicAdd(&cnt[cur], runlen);
      acc = 0.f; runlen = 0.f; cur = g;
    }
    acc += fmaxf(agg[(size_t)r * 64 + lane] * sc + sh, 0.f);
    runlen += 1.f;
  }
  unsafeAtomicAdd(&pool[cur * 64 + lane], acc);
  if (lane == 0) unsafeAtomicAdd(&cnt[cur], runlen);
}

__global__ void k_finalize(const float* __restrict__ pool, const float* __restrict__ cnt,
                           float* __restrict__ out) {
  int i = blockIdx.x * 256 + threadIdx.x;
  if (i < NG * 64) out[i] = pool[i] / fmaxf(cnt[i >> 6], 1.0f);
}

extern "C" void kernel_launch(void* const* d_in, const int* in_sizes, int n_in,
                              void* d_out, int out_size, void* d_ws, size_t ws_size,
                              hipStream_t stream) {
  const float* x = (const float*)d_in[0];
  const int* ei = (const int*)d_in[1];
  const int* batch = (const int*)d_in[3];
  const float* W1 = (const float*)d_in[4];
  const float* g1 = (const float*)d_in[6];
  const float* be1 = (const float*)d_in[7];
  const float* W2 = (const float*)d_in[8];
  const float* g2 = (const float*)d_in[10];
  const float* be2 = (const float*)d_in[11];
  const float* W3 = (const float*)d_in[12];
  const float* g3 = (const float*)d_in[14];
  const float* be3 = (const float*)d_in[15];
  float* out = (float*)d_out;

  char* ws = (char*)d_ws;
  float* agg = (float*)ws;      ws += (size_t)NN * 64 * 4;   // agg, row-major fp32
  __half* hq = (__half*)ws;     ws += (size_t)NN * 64 * 2;   // h*dinv, row-major fp16
  int* bpacked = (int*)ws;      ws += (size_t)NE * 4;
  int* edata = (int*)ws;        ws += (size_t)NE * 4;        // src only, dst-sorted
  int* rs = (int*)ws;           ws += 400016;                // (NN+1)*4 padded
  float* dinv = (float*)ws;     ws += (size_t)NN * 4;
  int* bcnt = (int*)ws;         ws += (size_t)NBUCK * NBLK * 4;
  int* boff = (int*)ws;         ws += (size_t)NBUCK * NBLK * 4;
  int* btot = (int*)ws;         ws += 512 * 4;
  int* bbase = (int*)ws;        ws += 512 * 4;
  float* statsP = (float*)ws;   ws += (size_t)3 * NSLOT * 128 * 4;  // slotted BN stats
  float* pool = (float*)ws;     ws += (size_t)NG * 64 * 4;
  float* cnt = (float*)ws;      ws += (size_t)NG * 4;
  __half* hWt = (__half*)ws;    ws += 32768;                 // W1t|W2t|W3t fp16

  // ---- CSR build (W-prep + zero-inits fused into the first kernel) ----
  k_bhist<<<NBLK, 256, 0, stream>>>(ei, bcnt, W1, W2, W3, hWt, pool, cnt, statsP);
  k_scan1<<<NBUCK, NBLK, 0, stream>>>(bcnt, boff, btot);
  k_scan2<<<1, 512, 0, stream>>>(btot, bbase);
  k_bscatter<<<NBLK, 256, 0, stream>>>(ei, boff, bbase, bpacked);
  k_sortfill<<<NBUCK, 256, 0, stream>>>(bpacked, boff, bbase, dinv, rs, edata);

  const float* gs[3] = {g1, g2, g3};
  const float* bes[3] = {be1, be2, be3};
  const __half* Wts[3] = {hWt, hWt + 64 * 128, hWt + 64 * 128 + 64 * 64};

  for (int layer = 0; layer < 3; layer++) {
    if (layer == 0)
      k_gemm<128, false><<<1024, 256, 0, stream>>>(x, nullptr, nullptr, nullptr,
                                                   Wts[0], dinv, hq);
    else
      k_gemm<64, true><<<1024, 256, 0, stream>>>(agg, statsP + NSLOT * 128 * (layer - 1),
                                                 gs[layer - 1], bes[layer - 1],
                                                 Wts[layer], dinv, hq);
    k_gather<<<GGRID, 256, 0, stream>>>(hq, edata, rs, dinv, agg,
                                        statsP + NSLOT * 128 * layer);
    if (layer == 2) {
      k_apply_pool<<<1024, 256, 0, stream>>>(agg, statsP + NSLOT * 128 * 2, g3, be3,
                                             batch, pool, cnt);
      k_finalize<<<(NG * 64 + 255) / 256, 256, 0, stream>>>(pool, cnt, out);
    }
  }
}